// Round 16
// baseline (495.162 us; speedup 1.0000x reference)
//
#include <hip/hip_runtime.h>
#include <hip/hip_bf16.h>
#include <stdint.h>

#define T_TOK 1024
#define H_DIM 2048
#define I_DIM 1408
#define E_NUM 16
#define K_TOP 4
#define IS_DIM 2816
#define BK 64
#define BKP 72     // padded LDS row stride (elements); 144B keeps 16B alignment
#define BM 256
#define NT_MAX 40  // 32 routed max + 8 shared tiles

typedef __hip_bfloat16 bf;
typedef __attribute__((ext_vector_type(8))) __bf16 bf16x8;
typedef __attribute__((ext_vector_type(4))) float f32x4;

// async global->LDS, 16B per lane; LDS dest wave-uniform base + lane*16
__device__ __forceinline__ void gload16(const void* g, void* l) {
  __builtin_amdgcn_global_load_lds((const __attribute__((address_space(1))) void*)g,
                                   (__attribute__((address_space(3))) void*)l, 16, 0, 0);
}

// ---------------- cast hidden states fp32 -> bf16 ----------------
__global__ void cvt_x_kernel(const float* __restrict__ in, bf* __restrict__ out) {
  int i = blockIdx.x * blockDim.x + threadIdx.x;
  float4 v = reinterpret_cast<const float4*>(in)[i];
  int b = i * 4;
  out[b + 0] = __float2bfloat16(v.x);
  out[b + 1] = __float2bfloat16(v.y);
  out[b + 2] = __float2bfloat16(v.z);
  out[b + 3] = __float2bfloat16(v.w);
}

// ---------------- gate: logits (fp32, exact), softmax, top-4 ----------------
__global__ void gate_topk_kernel(const float* __restrict__ x, const float* __restrict__ gw,
                                 int* __restrict__ topk_idx, float* __restrict__ topk_w) {
  int t = blockIdx.x;
  int lane = threadIdx.x;  // 64
  float acc[E_NUM];
#pragma unroll
  for (int e = 0; e < E_NUM; e++) acc[e] = 0.f;
  const float* xt = x + (long)t * H_DIM;
  for (int h = lane; h < H_DIM; h += 64) {
    float xv = xt[h];
#pragma unroll
    for (int e = 0; e < E_NUM; e++) acc[e] += xv * gw[e * H_DIM + h];
  }
#pragma unroll
  for (int e = 0; e < E_NUM; e++) {
    float v = acc[e];
    for (int off = 32; off; off >>= 1) v += __shfl_xor(v, off, 64);
    acc[e] = v;
  }
  if (lane == 0) {
    float m = acc[0];
#pragma unroll
    for (int e = 1; e < E_NUM; e++) m = fmaxf(m, acc[e]);
    float sc[E_NUM];
    float s = 0.f;
#pragma unroll
    for (int e = 0; e < E_NUM; e++) { sc[e] = expf(acc[e] - m); s += sc[e]; }
    float inv = 1.f / s;
#pragma unroll
    for (int e = 0; e < E_NUM; e++) sc[e] *= inv;
    for (int k = 0; k < K_TOP; k++) {
      int bi = 0;
      float bv = sc[0];
      for (int e = 1; e < E_NUM; e++)
        if (sc[e] > bv) { bv = sc[e]; bi = e; }   // strict > : first index wins ties
      topk_idx[t * K_TOP + k] = bi;
      topk_w[t * K_TOP + k] = bv;
      sc[bi] = -1.f;
    }
  }
}

// --------- build token lists: routed (256-row tiles) + 8 shared-expert tiles ---------
// rows[] stores p = t*8 + k; k in 0..3 routed slot, 4/5 shared halves.
__global__ void build_lists_kernel(const int* __restrict__ topk_idx,
                                   int* __restrict__ rows, int* __restrict__ tile_expert,
                                   int* __restrict__ n_tiles) {
  __shared__ int cnt[E_NUM], cur[E_NUM], s_tb;
  int tid = threadIdx.x;
  if (tid < E_NUM) cnt[tid] = 0;
  __syncthreads();
  for (int p = tid; p < T_TOK * K_TOP; p += blockDim.x)
    atomicAdd(&cnt[topk_idx[p]], 1);
  __syncthreads();
  if (tid == 0) {
    int tb = 0;
    for (int e = 0; e < E_NUM; e++) {
      int nt = (cnt[e] + BM - 1) / BM;
      cur[e] = tb * BM;
      for (int j = 0; j < nt; j++) tile_expert[tb + j] = e;
      tb += nt;
    }
    for (int j = 0; j < 8; j++) tile_expert[tb + j] = 16 + (j >> 2);  // shared halves
    s_tb = tb;
    *n_tiles = tb + 8;
  }
  __syncthreads();
  int tb = s_tb;
  for (int r = tid; r < NT_MAX * BM; r += blockDim.x) rows[r] = -1;
  __syncthreads();
  for (int p = tid; p < T_TOK * K_TOP; p += blockDim.x) {
    int t = p >> 2, k = p & 3;
    int e = topk_idx[p];
    int slot = atomicAdd(&cur[e], 1);
    rows[slot] = t * 8 + k;
  }
  // shared fill: 2 halves x 4 tiles x 256 tokens
  for (int idx = tid; idx < 8 * BM; idx += blockDim.x) {
    int j = idx >> 8, r = idx & 255;
    int t = (j & 3) * BM + r;
    rows[(tb + j) * BM + r] = t * 8 + 4 + (j >> 2);
  }
}

// ============ unified gate+up GEMM (producer/consumer): act = silu(X Wg)*(X Wu) ============
// BM=256, BN=64, 512 threads. Waves 0-3 = consumers (MFMA only, hold acc);
// waves 4-7 = producers (stage A via gload_lds + B fp32->bf16 reg staging; no MFMA).
// Double-buffered LDS, ONE s_barrier per K-step: producer's load latency runs
// concurrently with consumer MFMA -- the serial load->drain->MFMA chain is broken.
__launch_bounds__(512, 2)
__global__ void gemm_gateup_kernel(const bf* __restrict__ xb,
                                   const int* __restrict__ rows,
                                   const int* __restrict__ tile_expert,
                                   const int* __restrict__ n_tiles,
                                   const float* __restrict__ Wg,
                                   const float* __restrict__ Wu,
                                   const float* __restrict__ SWg,
                                   const float* __restrict__ SWu,
                                   bf* __restrict__ act) {
  // XCD-chunked decode: nwg = 22*40 = 880 (q=110); rt fastest within chunk
  int bid = blockIdx.x;
  int idx = (bid & 7) * 110 + (bid >> 3);
  int x = idx / NT_MAX, rt = idx % NT_MAX;
  if (rt >= *n_tiles) return;
  int e = tile_expert[rt];
  bool sh = e >= 16;
  const float* gbase = sh ? (SWg + (e - 16) * I_DIM) : (Wg + (long)e * H_DIM * I_DIM);
  const float* ubase = sh ? (SWu + (e - 16) * I_DIM) : (Wu + (long)e * H_DIM * I_DIM);
  long bstride = sh ? IS_DIM : I_DIM;
  int i0 = x * 64;

  __shared__ bf lA[2][BM * BK];        // 64 KB  (A, src-XOR-swizzled chunks)
  __shared__ bf lB2[2][2][64 * BKP];   // 36.9 KB ([buf][mat][n*BKP + swz-chunk])

  int tid = threadIdx.x, w = tid >> 6, lane = tid & 63;
  int l15 = lane & 15, lhi = lane >> 4;
  bool producer = w >= 4;
  int pw = w & 3;
  int sswz = (((lane & 7) ^ (lane >> 3)) * 8);  // A source chunk offset (elements)

  // -------- producer maps --------
  int ptid = tid & 255;                          // 0..255 for producer waves
  int nq = ptid & 15, mt = (ptid >> 4) & 1, kg = ptid >> 5;  // r10-proven B map
  int bco = (kg ^ (nq & 7)) * 8;                 // B write chunk slot
  const float* psrc = (mt ? ubase : gbase) + i0 + nq * 4 + (long)(kg * 8) * bstride;

  // A gather: 8 gload16/producer-lane covers 256 rows (32-row groups)
  const bf* asrc[8];
#pragma unroll
  for (int i = 0; i < 8; i++) {
    int rr = rt * BM + i * 32 + pw * 8 + (lane >> 3);
    int p = rows[rr];
    int tok = (p >= 0) ? (p >> 3) : 0;
    asrc[i] = xb + (long)tok * H_DIM + sswz;
  }

  // -------- consumer accumulators (wave tile 64 rows x 64 cols, both mats) --------
  f32x4 accg[4][4], accu[4][4];
  f32x4 z4 = {0.f, 0.f, 0.f, 0.f};
#pragma unroll
  for (int m = 0; m < 4; m++)
#pragma unroll
    for (int n = 0; n < 4; n++) { accg[m][n] = z4; accu[m][n] = z4; }

#define GU_PSTAGE(T, NB)                                                             \
  {                                                                                  \
    float4 v[8];                                                                     \
    const float* p_ = psrc + (long)(T) * BK * bstride;                               \
    _Pragma("unroll") for (int j = 0; j < 8; j++)                                    \
        v[j] = *reinterpret_cast<const float4*>(p_ + (long)j * bstride);             \
    _Pragma("unroll") for (int i = 0; i < 8; i++)                                    \
        gload16(asrc[i] + (T) * BK, &lA[NB][(i * 32 + pw * 8) * BK]);                \
    _Pragma("unroll") for (int c = 0; c < 4; c++) {                                  \
      union { bf16x8 vv; bf s[8]; } o;                                               \
      _Pragma("unroll") for (int j = 0; j < 8; j++)                                  \
          o.s[j] = __float2bfloat16(((const float*)&v[j])[c]);                       \
      *reinterpret_cast<bf16x8*>(&lB2[NB][mt][(nq * 4 + c) * BKP + bco]) = o.vv;     \
    }                                                                                \
  }

#define GU_MFMA(CB)                                                                  \
  {                                                                                  \
    _Pragma("unroll") for (int kk = 0; kk < 2; kk++) {                               \
      bf16x8 af[4];                                                                  \
      _Pragma("unroll") for (int m = 0; m < 4; m++)                                  \
          af[m] = *reinterpret_cast<const bf16x8*>(                                  \
              &lA[CB][(w * 64 + m * 16 + l15) * BK + (((kk * 4 + lhi) ^ (l15 & 7)) * 8)]); \
      _Pragma("unroll") for (int n = 0; n < 4; n++) {                                \
        int nrow = n * 16 + l15;                                                     \
        int bch = ((kk * 4 + lhi) ^ ((nrow >> 2) & 7)) * 8;                          \
        bf16x8 gf = *reinterpret_cast<const bf16x8*>(&lB2[CB][0][nrow * BKP + bch]); \
        bf16x8 uf = *reinterpret_cast<const bf16x8*>(&lB2[CB][1][nrow * BKP + bch]); \
        _Pragma("unroll") for (int m = 0; m < 4; m++) {                              \
          accg[m][n] = __builtin_amdgcn_mfma_f32_16x16x32_bf16(af[m], gf, accg[m][n], 0, 0, 0); \
          accu[m][n] = __builtin_amdgcn_mfma_f32_16x16x32_bf16(af[m], uf, accu[m][n], 0, 0, 0); \
        }                                                                            \
      }                                                                              \
    }                                                                                \
  }

  const int NT = H_DIM / BK;  // 32
  if (producer) {
    GU_PSTAGE(0, 0);
    asm volatile("s_waitcnt vmcnt(0) lgkmcnt(0)" ::: "memory");
  }
  __builtin_amdgcn_sched_barrier(0);
  __builtin_amdgcn_s_barrier();
  __builtin_amdgcn_sched_barrier(0);

  for (int t = 0; t < NT; ++t) {
    int cur = t & 1, nxt = cur ^ 1;
    if (producer) {
      if (t + 1 < NT) {
        GU_PSTAGE(t + 1, nxt);
        asm volatile("s_waitcnt vmcnt(0) lgkmcnt(0)" ::: "memory");
      }
    } else {
      GU_MFMA(cur);
    }
    __builtin_amdgcn_sched_barrier(0);
    __builtin_amdgcn_s_barrier();
    __builtin_amdgcn_sched_barrier(0);
  }
#undef GU_PSTAGE
#undef GU_MFMA

  if (!producer) {
#pragma unroll
    for (int m = 0; m < 4; m++)
#pragma unroll
      for (int n = 0; n < 4; n++)
#pragma unroll
        for (int r2 = 0; r2 < 4; r2++) {
          float gv = accg[m][n][r2];
          float uv = accu[m][n][r2];
          float s = (gv / (1.f + __expf(-gv))) * uv;          // silu(g)*u
          int row = rt * BM + w * 64 + m * 16 + lhi * 4 + r2; // C: row=(lane>>4)*4+reg
          int col = i0 + n * 16 + l15;                        //    col=lane&15 [m89]
          act[(long)row * I_DIM + col] = __float2bfloat16(s);
        }
  }
}

// ============ unified down GEMM (producer/consumer): outp[p] = act_tile @ Wd ============
// BM=256, BN=128, 512 threads. Consumers: wave tile 64x128 (acc 4x8).
__launch_bounds__(512, 2)
__global__ void gemm_down_kernel(const bf* __restrict__ A,
                                 const int* __restrict__ rows,
                                 const int* __restrict__ tile_expert,
                                 const int* __restrict__ n_tiles,
                                 const float* __restrict__ Wd,
                                 const float* __restrict__ SWd,
                                 bf* __restrict__ outp) {
  // nwg = 16*40 = 640 (q=80); rt fastest within chunk
  int bid = blockIdx.x;
  int idx = (bid & 7) * 80 + (bid >> 3);
  int x = idx / NT_MAX, rt = idx % NT_MAX;
  if (rt >= *n_tiles) return;
  int e = tile_expert[rt];
  bool sh = e >= 16;
  const float* bbase = sh ? (SWd + (long)(e - 16) * I_DIM * H_DIM)
                          : (Wd + (long)e * I_DIM * H_DIM);
  int h0 = x * 128;

  __shared__ bf lA[2][BM * BK];      // 64 KB
  __shared__ bf lB[2][128 * BKP];    // 36.9 KB
  __shared__ int rowsl[BM];

  int tid = threadIdx.x, w = tid >> 6, lane = tid & 63;
  int l15 = lane & 15, lhi = lane >> 4;
  bool producer = w >= 4;
  int pw = w & 3;
  int sswz = (((lane & 7) ^ (lane >> 3)) * 8);
  if (tid < BM) rowsl[tid] = rows[rt * BM + tid];   // consumers own epilogue data

  // producer maps (r10-proven down B map)
  int ptid = tid & 255;
  int ng = ptid & 31, kg = ptid >> 5;
  int bco = (kg ^ (ng & 7)) * 8;
  const float* psrc = bbase + h0 + ng * 4 + (long)(kg * 8) * H_DIM;

  const bf* asrc[8];
#pragma unroll
  for (int i = 0; i < 8; i++)
    asrc[i] = A + (long)(rt * BM + i * 32 + pw * 8 + (lane >> 3)) * I_DIM + sswz;

  f32x4 acc[4][8];
  f32x4 z4 = {0.f, 0.f, 0.f, 0.f};
#pragma unroll
  for (int m = 0; m < 4; m++)
#pragma unroll
    for (int n = 0; n < 8; n++) acc[m][n] = z4;

#define DN_PSTAGE(T, NB)                                                             \
  {                                                                                  \
    float4 v[8];                                                                     \
    const float* p_ = psrc + (long)(T) * BK * H_DIM;                                 \
    _Pragma("unroll") for (int j = 0; j < 8; j++)                                    \
        v[j] = *reinterpret_cast<const float4*>(p_ + (long)j * H_DIM);               \
    _Pragma("unroll") for (int i = 0; i < 8; i++)                                    \
        gload16(asrc[i] + (T) * BK, &lA[NB][(i * 32 + pw * 8) * BK]);                \
    _Pragma("unroll") for (int c = 0; c < 4; c++) {                                  \
      union { bf16x8 vv; bf s[8]; } o;                                               \
      _Pragma("unroll") for (int j = 0; j < 8; j++)                                  \
          o.s[j] = __float2bfloat16(((const float*)&v[j])[c]);                       \
      *reinterpret_cast<bf16x8*>(&lB[NB][(ng * 4 + c) * BKP + bco]) = o.vv;          \
    }                                                                                \
  }

#define DN_MFMA(CB)                                                                  \
  {                                                                                  \
    _Pragma("unroll") for (int kk = 0; kk < 2; kk++) {                               \
      bf16x8 af[4];                                                                  \
      _Pragma("unroll") for (int m = 0; m < 4; m++)                                  \
          af[m] = *reinterpret_cast<const bf16x8*>(                                  \
              &lA[CB][(w * 64 + m * 16 + l15) * BK + (((kk * 4 + lhi) ^ (l15 & 7)) * 8)]); \
      _Pragma("unroll") for (int n = 0; n < 8; n++) {                                \
        int nrow = n * 16 + l15;                                                     \
        int bch = ((kk * 4 + lhi) ^ ((nrow >> 2) & 7)) * 8;                          \
        bf16x8 bfr = *reinterpret_cast<const bf16x8*>(&lB[CB][nrow * BKP + bch]);    \
        _Pragma("unroll") for (int m = 0; m < 4; m++)                                \
            acc[m][n] = __builtin_amdgcn_mfma_f32_16x16x32_bf16(af[m], bfr, acc[m][n], 0, 0, 0); \
      }                                                                              \
    }                                                                                \
  }

  const int NT = I_DIM / BK;  // 22
  if (producer) {
    DN_PSTAGE(0, 0);
    asm volatile("s_waitcnt vmcnt(0) lgkmcnt(0)" ::: "memory");
  }
  __builtin_amdgcn_sched_barrier(0);
  __builtin_amdgcn_s_barrier();
  __builtin_amdgcn_sched_barrier(0);

  for (int t = 0; t < NT; ++t) {
    int cur = t & 1, nxt = cur ^ 1;
    if (producer) {
      if (t + 1 < NT) {
        DN_PSTAGE(t + 1, nxt);
        asm volatile("s_waitcnt vmcnt(0) lgkmcnt(0)" ::: "memory");
      }
    } else {
      DN_MFMA(cur);
    }
    __builtin_amdgcn_sched_barrier(0);
    __builtin_amdgcn_s_barrier();
    __builtin_amdgcn_sched_barrier(0);
  }
#undef DN_PSTAGE
#undef DN_MFMA

  if (!producer) {
#pragma unroll
    for (int m = 0; m < 4; m++)
#pragma unroll
      for (int n = 0; n < 8; n++)
#pragma unroll
        for (int r2 = 0; r2 < 4; r2++) {
          int lrow = w * 64 + m * 16 + lhi * 4 + r2;
          int col = h0 + n * 16 + l15;
          int p = rowsl[lrow];
          if (p >= 0) outp[(long)p * H_DIM + col] = __float2bfloat16(acc[m][n][r2]);
        }
  }
}

// ------- combine (vectorized): out = sum_k w_k*outp[t*8+k] + outp[t*8+4] + outp[t*8+5] -------
__global__ void combine_kernel(const bf* __restrict__ outp,
                               const float* __restrict__ topk_w,
                               float* __restrict__ out) {
  int g = blockIdx.x * blockDim.x + threadIdx.x;  // 8-elem group
  int t = g >> 8;                                 // 256 groups per token (H=2048)
  int h = (g & 255) * 8;
  const bf* base = outp + (long)t * 8 * H_DIM + h;
  float w0 = topk_w[t * 4 + 0], w1 = topk_w[t * 4 + 1];
  float w2 = topk_w[t * 4 + 2], w3 = topk_w[t * 4 + 3];
  bf16x8 s4 = *reinterpret_cast<const bf16x8*>(base + 4 * H_DIM);
  bf16x8 s5 = *reinterpret_cast<const bf16x8*>(base + 5 * H_DIM);
  bf16x8 r0 = *reinterpret_cast<const bf16x8*>(base + 0 * H_DIM);
  bf16x8 r1 = *reinterpret_cast<const bf16x8*>(base + 1 * H_DIM);
  bf16x8 r2 = *reinterpret_cast<const bf16x8*>(base + 2 * H_DIM);
  bf16x8 r3 = *reinterpret_cast<const bf16x8*>(base + 3 * H_DIM);
  float acc[8];
#pragma unroll
  for (int j = 0; j < 8; j++) {
    acc[j] = (float)s4[j] + (float)s5[j]
           + w0 * (float)r0[j] + w1 * (float)r1[j]
           + w2 * (float)r2[j] + w3 * (float)r3[j];
  }
  float4* o = reinterpret_cast<float4*>(out + (long)t * H_DIM + h);
  o[0] = make_float4(acc[0], acc[1], acc[2], acc[3]);
  o[1] = make_float4(acc[4], acc[5], acc[6], acc[7]);
}

extern "C" void kernel_launch(void* const* d_in, const int* in_sizes, int n_in,
                              void* d_out, int out_size, void* d_ws, size_t ws_size,
                              hipStream_t stream) {
  const float* x     = (const float*)d_in[0];
  const float* gw    = (const float*)d_in[1];
  const float* wgate = (const float*)d_in[2];
  const float* wup   = (const float*)d_in[3];
  const float* wdown = (const float*)d_in[4];
  const float* swg   = (const float*)d_in[5];
  const float* swu   = (const float*)d_in[6];
  const float* swd   = (const float*)d_in[7];
  float* out = (float*)d_out;

  char* ws = (char*)d_ws;
  size_t off = 0;
  auto alloc = [&](size_t bytes) {
    void* p = ws + off;
    off += (bytes + 255) & ~(size_t)255;
    return p;
  };

  bf* xb   = (bf*)alloc((size_t)T_TOK * H_DIM * 2);
  bf* act  = (bf*)alloc((size_t)NT_MAX * BM * I_DIM * 2);
  bf* outp = (bf*)alloc((size_t)T_TOK * 8 * H_DIM * 2);
  int*   topk_idx = (int*)alloc(T_TOK * K_TOP * 4);
  float* topk_w   = (float*)alloc(T_TOK * K_TOP * 4);
  int*   rowsbuf  = (int*)alloc(NT_MAX * BM * 4);
  int*   tile_exp = (int*)alloc(NT_MAX * 4);
  int*   n_tiles  = (int*)alloc(64);
  (void)ws_size; (void)in_sizes; (void)n_in; (void)out_size;

  hipLaunchKernelGGL(cvt_x_kernel, dim3(T_TOK * H_DIM / 1024), dim3(256), 0, stream, x, xb);
  hipLaunchKernelGGL(gate_topk_kernel, dim3(T_TOK), dim3(64), 0, stream, x, gw, topk_idx, topk_w);
  hipLaunchKernelGGL(build_lists_kernel, dim3(1), dim3(256), 0, stream, topk_idx, rowsbuf, tile_exp, n_tiles);

  // unified gate+up (routed + shared halves) -> act   grid: 22 N-panels x 40 tiles = 880
  hipLaunchKernelGGL(gemm_gateup_kernel, dim3(22 * NT_MAX), dim3(512), 0, stream,
                     xb, rowsbuf, tile_exp, n_tiles, wgate, wup, swg, swu, act);
  // unified down -> outp   grid: 16 N-panels x 40 tiles = 640
  hipLaunchKernelGGL(gemm_down_kernel, dim3(16 * NT_MAX), dim3(512), 0, stream,
                     act, rowsbuf, tile_exp, n_tiles, wdown, swd, outp);

  hipLaunchKernelGGL(combine_kernel, dim3(T_TOK * H_DIM / 8 / 256), dim3(256), 0, stream,
                     outp, topk_w, out);
}

// Round 17
// 316.137 us; speedup vs baseline: 1.5663x; 1.5663x over previous
//
#include <hip/hip_runtime.h>
#include <hip/hip_bf16.h>
#include <stdint.h>

#define T_TOK 1024
#define H_DIM 2048
#define I_DIM 1408
#define E_NUM 16
#define K_TOP 4
#define IS_DIM 2816
#define BK 64
#define BKP 72     // padded LDS row stride (elements); 144B = 16*9 keeps 16B alignment
#define BM 128
#define NT_MAX 64  // 48 routed max + 16 shared tiles

typedef __hip_bfloat16 bf;
typedef __attribute__((ext_vector_type(8))) __bf16 bf16x8;
typedef __attribute__((ext_vector_type(4))) float f32x4;

// async global->LDS, 16B per lane; LDS dest is wave-uniform base + lane*16
__device__ __forceinline__ void gload16(const void* g, void* l) {
  __builtin_amdgcn_global_load_lds((const __attribute__((address_space(1))) void*)g,
                                   (__attribute__((address_space(3))) void*)l, 16, 0, 0);
}

// ---------------- cast hidden states fp32 -> bf16 ----------------
__global__ void cvt_x_kernel(const float* __restrict__ in, bf* __restrict__ out) {
  int i = blockIdx.x * blockDim.x + threadIdx.x;  // indexes float4
  float4 v = reinterpret_cast<const float4*>(in)[i];
  int b = i * 4;
  out[b + 0] = __float2bfloat16(v.x);
  out[b + 1] = __float2bfloat16(v.y);
  out[b + 2] = __float2bfloat16(v.z);
  out[b + 3] = __float2bfloat16(v.w);
}

// ---------------- gate: logits (fp32, exact), softmax, top-4 ----------------
__global__ void gate_topk_kernel(const float* __restrict__ x, const float* __restrict__ gw,
                                 int* __restrict__ topk_idx, float* __restrict__ topk_w) {
  int t = blockIdx.x;
  int lane = threadIdx.x;  // 64
  float acc[E_NUM];
#pragma unroll
  for (int e = 0; e < E_NUM; e++) acc[e] = 0.f;
  const float* xt = x + (long)t * H_DIM;
  for (int h = lane; h < H_DIM; h += 64) {
    float xv = xt[h];
#pragma unroll
    for (int e = 0; e < E_NUM; e++) acc[e] += xv * gw[e * H_DIM + h];
  }
#pragma unroll
  for (int e = 0; e < E_NUM; e++) {
    float v = acc[e];
    for (int off = 32; off; off >>= 1) v += __shfl_xor(v, off, 64);
    acc[e] = v;
  }
  if (lane == 0) {
    float m = acc[0];
#pragma unroll
    for (int e = 1; e < E_NUM; e++) m = fmaxf(m, acc[e]);
    float sc[E_NUM];
    float s = 0.f;
#pragma unroll
    for (int e = 0; e < E_NUM; e++) { sc[e] = expf(acc[e] - m); s += sc[e]; }
    float inv = 1.f / s;
#pragma unroll
    for (int e = 0; e < E_NUM; e++) sc[e] *= inv;
    for (int k = 0; k < K_TOP; k++) {
      int bi = 0;
      float bv = sc[0];
      for (int e = 1; e < E_NUM; e++)
        if (sc[e] > bv) { bv = sc[e]; bi = e; }   // strict > : first index wins ties
      topk_idx[t * K_TOP + k] = bi;
      topk_w[t * K_TOP + k] = bv;
      sc[bi] = -1.f;
    }
  }
}

// --------- build token lists: routed (128-row tiles) + 16 shared-expert tiles ---------
// rows[] stores p = t*8 + k; k in 0..3 routed slot, 4/5 shared halves.
__global__ void build_lists_kernel(const int* __restrict__ topk_idx,
                                   int* __restrict__ rows, int* __restrict__ tile_expert,
                                   int* __restrict__ n_tiles) {
  __shared__ int cnt[E_NUM], cur[E_NUM], s_tb;
  int tid = threadIdx.x;
  if (tid < E_NUM) cnt[tid] = 0;
  __syncthreads();
  for (int p = tid; p < T_TOK * K_TOP; p += blockDim.x)
    atomicAdd(&cnt[topk_idx[p]], 1);
  __syncthreads();
  if (tid == 0) {
    int tb = 0;
    for (int e = 0; e < E_NUM; e++) {
      int nt = (cnt[e] + BM - 1) / BM;
      cur[e] = tb * BM;
      for (int j = 0; j < nt; j++) tile_expert[tb + j] = e;
      tb += nt;
    }
    for (int j = 0; j < 16; j++) tile_expert[tb + j] = 16 + (j >> 3);  // shared halves
    s_tb = tb;
    *n_tiles = tb + 16;
  }
  __syncthreads();
  int tb = s_tb;
  for (int r = tid; r < NT_MAX * BM; r += blockDim.x) rows[r] = -1;
  __syncthreads();
  // routed scatter
  for (int p = tid; p < T_TOK * K_TOP; p += blockDim.x) {
    int t = p >> 2, k = p & 3;
    int e = topk_idx[p];
    int slot = atomicAdd(&cur[e], 1);
    rows[slot] = t * 8 + k;
  }
  // shared fill: 2 halves x 8 tiles x 128 tokens
  for (int idx = tid; idx < 16 * BM; idx += blockDim.x) {
    int j = idx >> 7, r = idx & 127;
    int t = (j & 7) * BM + r;
    rows[(tb + j) * BM + r] = t * 8 + 4 + (j >> 3);
  }
}

// ============ unified gate+up GEMM: act = silu(X Wg) * (X Wu) ============
// BM=128, BN=64. LDS double-buffered, ONE barrier per K-step:
//   issue(t+1 -> buf^1) | MFMA(buf) | cvt+write(t+1 -> buf^1) | barrier
// so the barrier's vmcnt(0) drain overlaps the whole MFMA phase.
// 256 threads: half stage G, half stage U (mt bit).
__launch_bounds__(256, 2)
__global__ void gemm_gateup_kernel(const bf* __restrict__ xb,
                                   const int* __restrict__ rows,
                                   const int* __restrict__ tile_expert,
                                   const int* __restrict__ n_tiles,
                                   const float* __restrict__ Wg,
                                   const float* __restrict__ Wu,
                                   const float* __restrict__ SWg,
                                   const float* __restrict__ SWu,
                                   bf* __restrict__ act) {
  // XCD-chunked decode: nwg = 22*64 = 1408 (q=176); rt fastest within chunk
  int bid = blockIdx.x;
  int idx = (bid & 7) * 176 + (bid >> 3);
  int x = idx >> 6, rt = idx & 63;
  if (rt >= *n_tiles) return;
  int e = tile_expert[rt];
  bool sh = e >= 16;
  const float* gbase = sh ? (SWg + (e - 16) * I_DIM) : (Wg + (long)e * H_DIM * I_DIM);
  const float* ubase = sh ? (SWu + (e - 16) * I_DIM) : (Wu + (long)e * H_DIM * I_DIM);
  long bstride = sh ? IS_DIM : I_DIM;
  int i0 = x * 64;

  __shared__ bf lA[2][BM * BK];        // [buf][row*BK], source-XOR-swizzled chunks
  __shared__ bf lB2[2][2][64 * BKP];   // [buf][mat(G,U)][n*BKP + swz-chunk]

  int tid = threadIdx.x, w = tid >> 6, lane = tid & 63;
  int l15 = lane & 15, lhi = lane >> 4;
  int nq = tid & 15, mt = (tid >> 4) & 1, kg = tid >> 5;  // staging coords
  int sswz = (((lane & 7) ^ (lane >> 3)) * 8);            // A source chunk offset
  int bco = (kg ^ (nq & 7)) * 8;                          // B write chunk slot

  const bf* asrc[4];
#pragma unroll
  for (int i = 0; i < 4; i++) {
    int rr = rt * BM + i * 32 + w * 8 + (lane >> 3);
    int p = rows[rr];
    int tok = (p >= 0) ? (p >> 3) : 0;
    asrc[i] = xb + (long)tok * H_DIM + sswz;
  }

  const float* psrc = (mt ? ubase : gbase) + i0 + nq * 4 + (long)(kg * 8) * bstride;

  f32x4 accg[4][2], accu[4][2];
  f32x4 z4 = {0.f, 0.f, 0.f, 0.f};
#pragma unroll
  for (int m = 0; m < 4; m++)
#pragma unroll
    for (int n = 0; n < 2; n++) { accg[m][n] = z4; accu[m][n] = z4; }

  int wr = w >> 1, wc = w & 1;
  float4 v[8];

#define GU_ISSUE(T, NB)                                                            \
  {                                                                                \
    const float* p_ = psrc + (long)(T) * BK * bstride;                             \
    _Pragma("unroll") for (int j = 0; j < 8; j++)                                  \
        v[j] = *reinterpret_cast<const float4*>(p_ + (long)j * bstride);           \
    _Pragma("unroll") for (int i = 0; i < 4; i++)                                  \
        gload16(asrc[i] + (T) * BK, &lA[NB][(i * 32 + w * 8) * BK]);               \
  }

#define GU_WRITE(NB)                                                               \
  {                                                                                \
    _Pragma("unroll") for (int c = 0; c < 4; c++) {                                \
      union { bf16x8 vv; bf s[8]; } o;                                             \
      _Pragma("unroll") for (int j = 0; j < 8; j++)                                \
          o.s[j] = __float2bfloat16(((const float*)&v[j])[c]);                     \
      *reinterpret_cast<bf16x8*>(&lB2[NB][mt][(nq * 4 + c) * BKP + bco]) = o.vv;   \
    }                                                                              \
  }

#define GU_MFMA(CB)                                                                \
  {                                                                                \
    _Pragma("unroll") for (int kk = 0; kk < 2; kk++) {                             \
      bf16x8 af[4];                                                                \
      _Pragma("unroll") for (int m = 0; m < 4; m++)                                \
          af[m] = *reinterpret_cast<const bf16x8*>(                                \
              &lA[CB][(wr * 64 + m * 16 + l15) * BK + (((kk * 4 + lhi) ^ (l15 & 7)) * 8)]); \
      _Pragma("unroll") for (int n = 0; n < 2; n++) {                              \
        int nrow = wc * 32 + n * 16 + l15;                                         \
        int bch = ((kk * 4 + lhi) ^ ((nrow >> 2) & 7)) * 8;                        \
        bf16x8 gf = *reinterpret_cast<const bf16x8*>(&lB2[CB][0][nrow * BKP + bch]); \
        bf16x8 uf = *reinterpret_cast<const bf16x8*>(&lB2[CB][1][nrow * BKP + bch]); \
        _Pragma("unroll") for (int m = 0; m < 4; m++) {                            \
          accg[m][n] = __builtin_amdgcn_mfma_f32_16x16x32_bf16(af[m], gf, accg[m][n], 0, 0, 0); \
          accu[m][n] = __builtin_amdgcn_mfma_f32_16x16x32_bf16(af[m], uf, accu[m][n], 0, 0, 0); \
        }                                                                          \
      }                                                                            \
    }                                                                              \
  }

  const int NT = H_DIM / BK;  // 32 (even)
  // prologue: stage step 0 into buf0
  GU_ISSUE(0, 0);
  GU_WRITE(0);
  __syncthreads();

  for (int t = 0; t < NT; t += 2) {
    // step t: compute buf0; stage t+1 -> buf1 (t<=NT-2 so t+1<NT always)
    GU_ISSUE(t + 1, 1);
    __builtin_amdgcn_sched_barrier(0);
    GU_MFMA(0);
    __builtin_amdgcn_sched_barrier(0);
    GU_WRITE(1);
    __syncthreads();
    // step t+1: compute buf1; stage t+2 -> buf0 (skip on last)
    if (t + 2 < NT) GU_ISSUE(t + 2, 0);
    __builtin_amdgcn_sched_barrier(0);
    GU_MFMA(1);
    __builtin_amdgcn_sched_barrier(0);
    if (t + 2 < NT) GU_WRITE(0);
    __syncthreads();
  }
#undef GU_ISSUE
#undef GU_WRITE
#undef GU_MFMA

#pragma unroll
  for (int m = 0; m < 4; m++)
#pragma unroll
    for (int n = 0; n < 2; n++)
#pragma unroll
      for (int r2 = 0; r2 < 4; r2++) {
        float gv = accg[m][n][r2];
        float uv = accu[m][n][r2];
        float s = (gv / (1.f + __expf(-gv))) * uv;            // silu(g)*u
        int row = rt * BM + wr * 64 + m * 16 + lhi * 4 + r2;  // C: row=(lane>>4)*4+reg
        int col = i0 + wc * 32 + n * 16 + l15;                //    col=lane&15 [m89]
        act[(long)row * I_DIM + col] = __float2bfloat16(s);
      }
}

// ============ unified down GEMM: outp[p] = act_tile @ Wd ============
// BM=128, BN=128, same double-buffer/one-barrier schedule.
__launch_bounds__(256, 2)
__global__ void gemm_down_kernel(const bf* __restrict__ A,
                                 const int* __restrict__ rows,
                                 const int* __restrict__ tile_expert,
                                 const int* __restrict__ n_tiles,
                                 const float* __restrict__ Wd,
                                 const float* __restrict__ SWd,
                                 bf* __restrict__ outp) {
  // nwg = 16*64 = 1024; q=128
  int bid = blockIdx.x;
  int idx = (bid & 7) * 128 + (bid >> 3);
  int x = idx >> 6, rt = idx & 63;
  if (rt >= *n_tiles) return;
  int e = tile_expert[rt];
  bool sh = e >= 16;
  const float* bbase = sh ? (SWd + (long)(e - 16) * I_DIM * H_DIM)
                          : (Wd + (long)e * I_DIM * H_DIM);
  int h0 = x * 128;

  __shared__ bf lA[2][BM * BK];
  __shared__ bf lB[2][128 * BKP];
  __shared__ int rowsl[BM];

  int tid = threadIdx.x, w = tid >> 6, lane = tid & 63;
  int l15 = lane & 15, lhi = lane >> 4;
  int kg = tid >> 5, ng = tid & 31;
  int sswz = (((lane & 7) ^ (lane >> 3)) * 8);
  int bco = (kg ^ (ng & 7)) * 8;
  if (tid < BM) rowsl[tid] = rows[rt * BM + tid];

  const bf* asrc[4];
#pragma unroll
  for (int i = 0; i < 4; i++)
    asrc[i] = A + (long)(rt * BM + i * 32 + w * 8 + (lane >> 3)) * I_DIM + sswz;

  const float* psrc = bbase + h0 + ng * 4 + (long)(kg * 8) * H_DIM;

  f32x4 acc[4][4];
  f32x4 z4 = {0.f, 0.f, 0.f, 0.f};
#pragma unroll
  for (int m = 0; m < 4; m++)
#pragma unroll
    for (int n = 0; n < 4; n++) acc[m][n] = z4;

  int wr = w >> 1, wc = w & 1;
  float4 v[8];

#define DN_ISSUE(T, NB)                                                            \
  {                                                                                \
    const float* p_ = psrc + (long)(T) * BK * H_DIM;                               \
    _Pragma("unroll") for (int j = 0; j < 8; j++)                                  \
        v[j] = *reinterpret_cast<const float4*>(p_ + (long)j * H_DIM);             \
    _Pragma("unroll") for (int i = 0; i < 4; i++)                                  \
        gload16(asrc[i] + (T) * BK, &lA[NB][(i * 32 + w * 8) * BK]);               \
  }

#define DN_WRITE(NB)                                                               \
  {                                                                                \
    _Pragma("unroll") for (int c = 0; c < 4; c++) {                                \
      union { bf16x8 vv; bf s[8]; } o;                                             \
      _Pragma("unroll") for (int j = 0; j < 8; j++)                                \
          o.s[j] = __float2bfloat16(((const float*)&v[j])[c]);                     \
      *reinterpret_cast<bf16x8*>(&lB[NB][(ng * 4 + c) * BKP + bco]) = o.vv;        \
    }                                                                              \
  }

#define DN_MFMA(CB)                                                                \
  {                                                                                \
    _Pragma("unroll") for (int kk = 0; kk < 2; kk++) {                             \
      bf16x8 af[4];                                                                \
      _Pragma("unroll") for (int m = 0; m < 4; m++)                                \
          af[m] = *reinterpret_cast<const bf16x8*>(                                \
              &lA[CB][(wr * 64 + m * 16 + l15) * BK + (((kk * 4 + lhi) ^ (l15 & 7)) * 8)]); \
      _Pragma("unroll") for (int n = 0; n < 4; n++) {                              \
        int nrow = wc * 64 + n * 16 + l15;                                         \
        int bch = ((kk * 4 + lhi) ^ ((nrow >> 2) & 7)) * 8;                        \
        bf16x8 bfr = *reinterpret_cast<const bf16x8*>(&lB[CB][nrow * BKP + bch]);  \
        _Pragma("unroll") for (int m = 0; m < 4; m++)                              \
            acc[m][n] = __builtin_amdgcn_mfma_f32_16x16x32_bf16(af[m], bfr, acc[m][n], 0, 0, 0); \
      }                                                                            \
    }                                                                              \
  }

  const int NT = I_DIM / BK;  // 22 (even)
  DN_ISSUE(0, 0);
  DN_WRITE(0);
  __syncthreads();

  for (int t = 0; t < NT; t += 2) {
    DN_ISSUE(t + 1, 1);
    __builtin_amdgcn_sched_barrier(0);
    DN_MFMA(0);
    __builtin_amdgcn_sched_barrier(0);
    DN_WRITE(1);
    __syncthreads();
    if (t + 2 < NT) DN_ISSUE(t + 2, 0);
    __builtin_amdgcn_sched_barrier(0);
    DN_MFMA(1);
    __builtin_amdgcn_sched_barrier(0);
    if (t + 2 < NT) DN_WRITE(0);
    __syncthreads();
  }
#undef DN_ISSUE
#undef DN_WRITE
#undef DN_MFMA

#pragma unroll
  for (int m = 0; m < 4; m++)
#pragma unroll
    for (int n = 0; n < 4; n++)
#pragma unroll
      for (int r2 = 0; r2 < 4; r2++) {
        int lrow = wr * 64 + m * 16 + lhi * 4 + r2;
        int col = h0 + wc * 64 + n * 16 + l15;
        int p = rowsl[lrow];
        if (p >= 0) outp[(long)p * H_DIM + col] = __float2bfloat16(acc[m][n][r2]);
      }
}

// ------- combine (vectorized): out = sum_k w_k*outp[t*8+k] + outp[t*8+4] + outp[t*8+5] -------
__global__ void combine_kernel(const bf* __restrict__ outp,
                               const float* __restrict__ topk_w,
                               float* __restrict__ out) {
  int g = blockIdx.x * blockDim.x + threadIdx.x;  // 8-elem group
  int t = g >> 8;                                 // 256 groups per token (H=2048)
  int h = (g & 255) * 8;
  const bf* base = outp + (long)t * 8 * H_DIM + h;
  float w0 = topk_w[t * 4 + 0], w1 = topk_w[t * 4 + 1];
  float w2 = topk_w[t * 4 + 2], w3 = topk_w[t * 4 + 3];
  bf16x8 s4 = *reinterpret_cast<const bf16x8*>(base + 4 * H_DIM);
  bf16x8 s5 = *reinterpret_cast<const bf16x8*>(base + 5 * H_DIM);
  bf16x8 r0 = *reinterpret_cast<const bf16x8*>(base + 0 * H_DIM);
  bf16x8 r1 = *reinterpret_cast<const bf16x8*>(base + 1 * H_DIM);
  bf16x8 r2 = *reinterpret_cast<const bf16x8*>(base + 2 * H_DIM);
  bf16x8 r3 = *reinterpret_cast<const bf16x8*>(base + 3 * H_DIM);
  float acc[8];
#pragma unroll
  for (int j = 0; j < 8; j++) {
    acc[j] = (float)s4[j] + (float)s5[j]
           + w0 * (float)r0[j] + w1 * (float)r1[j]
           + w2 * (float)r2[j] + w3 * (float)r3[j];
  }
  float4* o = reinterpret_cast<float4*>(out + (long)t * H_DIM + h);
  o[0] = make_float4(acc[0], acc[1], acc[2], acc[3]);
  o[1] = make_float4(acc[4], acc[5], acc[6], acc[7]);
}

extern "C" void kernel_launch(void* const* d_in, const int* in_sizes, int n_in,
                              void* d_out, int out_size, void* d_ws, size_t ws_size,
                              hipStream_t stream) {
  const float* x     = (const float*)d_in[0];
  const float* gw    = (const float*)d_in[1];
  const float* wgate = (const float*)d_in[2];
  const float* wup   = (const float*)d_in[3];
  const float* wdown = (const float*)d_in[4];
  const float* swg   = (const float*)d_in[5];
  const float* swu   = (const float*)d_in[6];
  const float* swd   = (const float*)d_in[7];
  float* out = (float*)d_out;

  char* ws = (char*)d_ws;
  size_t off = 0;
  auto alloc = [&](size_t bytes) {
    void* p = ws + off;
    off += (bytes + 255) & ~(size_t)255;
    return p;
  };

  bf* xb   = (bf*)alloc((size_t)T_TOK * H_DIM * 2);
  bf* act  = (bf*)alloc((size_t)NT_MAX * BM * I_DIM * 2);
  bf* outp = (bf*)alloc((size_t)T_TOK * 8 * H_DIM * 2);
  int*   topk_idx = (int*)alloc(T_TOK * K_TOP * 4);
  float* topk_w   = (float*)alloc(T_TOK * K_TOP * 4);
  int*   rowsbuf  = (int*)alloc(NT_MAX * BM * 4);
  int*   tile_exp = (int*)alloc(NT_MAX * 4);
  int*   n_tiles  = (int*)alloc(64);
  (void)ws_size; (void)in_sizes; (void)n_in; (void)out_size;

  hipLaunchKernelGGL(cvt_x_kernel, dim3(T_TOK * H_DIM / 1024), dim3(256), 0, stream, x, xb);
  hipLaunchKernelGGL(gate_topk_kernel, dim3(T_TOK), dim3(64), 0, stream, x, gw, topk_idx, topk_w);
  hipLaunchKernelGGL(build_lists_kernel, dim3(1), dim3(256), 0, stream, topk_idx, rowsbuf, tile_exp, n_tiles);

  // unified gate+up (routed + shared halves) -> act   grid: 22 N-panels x 64 tiles = 1408
  hipLaunchKernelGGL(gemm_gateup_kernel, dim3((I_DIM / 64) * NT_MAX), dim3(256), 0, stream,
                     xb, rowsbuf, tile_exp, n_tiles, wgate, wup, swg, swu, act);
  // unified down -> outp   grid: 16 N-panels x 64 tiles = 1024
  hipLaunchKernelGGL(gemm_down_kernel, dim3((H_DIM / 128) * NT_MAX), dim3(256), 0, stream,
                     act, rowsbuf, tile_exp, n_tiles, wdown, swd, outp);

  hipLaunchKernelGGL(combine_kernel, dim3(T_TOK * H_DIM / 8 / 256), dim3(256), 0, stream,
                     outp, topk_w, out);
}